// Round 4
// baseline (254.341 us; speedup 1.0000x reference)
//
#include <hip/hip_runtime.h>

#define N_B   262144
#define BM    128
#define KAUG  288      // 256 (h) + 32 (x-augmentation, only 3 used)
#define LDA   296      // hA row stride in halves: 256 h + 3 x-aug + pad; 148 dw == 20 mod 32
                       // -> 4-way bank groups on 32-row access (1.58x, accepted)

typedef _Float16 f16x8  __attribute__((ext_vector_type(8)));
typedef _Float16 f16x4  __attribute__((ext_vector_type(4)));
typedef float    f32x16 __attribute__((ext_vector_type(16)));

// ---------------------------------------------------------------------------
// Precompute (68 blocks, ~5 us):
//   blocks 0..63 : (l = b>>4, row-group ng = b&15) -> Mt[l][16ng..16ng+16)[*]
//   blocks 64..67: W1t[n][k] = W1[k][n] transpose.
// ---------------------------------------------------------------------------
__global__ void fno_precompute(const float* __restrict__ W1,
                               const float* __restrict__ fw,
                               const float* __restrict__ lw,
                               _Float16* __restrict__ Mt,    // [4][256][KAUG]
                               _Float16* __restrict__ W1t)   // [256][64]
{
    const int t = threadIdx.x;          // 0..255
    const int b = blockIdx.x;
    if (b < 64) {
        const int l  = b >> 4;
        const int ng = b & 15;
        __shared__ float cosTab[256];
        __shared__ float cs[256];
        cosTab[t] = cosf((float)t * (6.28318530717958647692f / 256.0f));
        __syncthreads();
        // cs[t] = irfft(fw_l)[t]
        {
            const float* fwl = fw + l * 129;
            float s = fwl[0];
            #pragma unroll 4
            for (int k = 1; k < 128; ++k)
                s += 2.0f * fwl[k] * cosTab[(k * t) & 255];
            s += fwl[128] * ((t & 1) ? -1.0f : 1.0f);
            cs[t] = s * (1.0f / 256.0f);
        }
        __syncthreads();
        for (int idx = t; idx < 16 * KAUG; idx += 256) {
            const int n = ng * 16 + idx / KAUG;
            const int k = idx % KAUG;
            float v = 0.0f;
            if (k < 253)               v = cs[(n - k - 3) & 255];  // conv: h[k] -> d[k+3]
            if (k == n)                v += lw[l * 256 + n];       // diagonal residual lw
            if (k >= 256 && k < 259)   v = cs[(n - (k - 256)) & 255]; // x rows
            Mt[((size_t)l * 256 + n) * KAUG + k] = (_Float16)v;
        }
    } else {
        const int base = (b - 64) * 4096;
        #pragma unroll
        for (int i = 0; i < 16; ++i) {
            const int idx = base + t + i * 256;
            const int n = idx >> 6, k = idx & 63;
            W1t[idx] = (_Float16)W1[k * 256 + n];
        }
    }
}

// ---------------------------------------------------------------------------
// Fused main kernel, 32x32x16 MFMA. Block = 128 rows x 256 threads (4 waves);
// wave w owns feature stripe [64w, 64w+64) = 2 tiles of 32.
// mfma(Mt_frag, h_frag): D has lane = h-row (lane&31), regs = 16 features
// (groups of 4 consecutive) -> f16x4 epilogue writes.
// x-augmentation lives in hA cols 256..258 (cols 259..295 zero), so the
// 18-step K-loop is uniform over hA.
// ---------------------------------------------------------------------------
__global__ __launch_bounds__(256, 2)
void fno_main(const float* __restrict__ mu,
              const float* __restrict__ x,
              const float* __restrict__ b1,
              const float* __restrict__ W2,
              const float* __restrict__ b2,
              const _Float16* __restrict__ Mt,
              const _Float16* __restrict__ W1t,
              float* __restrict__ out)
{
    __shared__ __align__(16) _Float16 hA[BM * LDA];   // 75,776 B
    __shared__ float b1s[256];
    __shared__ float W2s[256];
    __shared__ float red[BM];

    const int t    = threadIdx.x;
    const int w    = t >> 6;        // wave id: feature stripe 64*w
    const int lane = t & 63;
    const int i32  = lane & 31;     // Mt-frag feature / h-frag row / D h-row
    const int hi   = lane >> 5;     // k-half (inputs) / feature sub-offset (D)
    const int r0   = blockIdx.x * BM;

    // ---- stage mu -> hA cols 0..63 (fp16); zero aug cols 256..295 ----
    {
        const float4* mu4 = (const float4*)mu + (size_t)r0 * 16;  // 16 float4 per row
        #pragma unroll
        for (int j = 0; j < 8; ++j) {
            int f = t + 256 * j;
            int row = f >> 4, c4 = f & 15;
            float4 v = mu4[f];
            f16x4 h;
            h[0] = (_Float16)v.x; h[1] = (_Float16)v.y;
            h[2] = (_Float16)v.z; h[3] = (_Float16)v.w;
            *(f16x4*)&hA[row * LDA + c4 * 4] = h;
        }
        f16x8 z8 = {(_Float16)0, (_Float16)0, (_Float16)0, (_Float16)0,
                    (_Float16)0, (_Float16)0, (_Float16)0, (_Float16)0};
        for (int idx = t; idx < BM * 5; idx += 256) {     // 128 rows x 40 halves
            int row = idx / 5, c = 256 + 8 * (idx % 5);
            *(f16x8*)&hA[row * LDA + c] = z8;
        }
    }
    __syncthreads();   // aug region zeroed before x insert
    if (t < BM) {
        const float* xp = x + (size_t)(r0 + t) * 3;
        hA[t * LDA + 256] = (_Float16)xp[0];
        hA[t * LDA + 257] = (_Float16)xp[1];
        hA[t * LDA + 258] = (_Float16)xp[2];
    }
    b1s[t] = b1[t];
    W2s[t] = W2[t];
    __syncthreads();

    f32x16 acc[2][4];   // [feature-tile][row-tile], 128 regs

    // ================= encoder: h = relu(mu @ W1 + b1), K = 64 =================
    #pragma unroll
    for (int ft = 0; ft < 2; ++ft)
        #pragma unroll
        for (int rt = 0; rt < 4; ++rt)
            acc[ft][rt] = (f32x16)(0.f);

    #pragma unroll
    for (int ks = 0; ks < 4; ++ks) {
        const int kb = ks * 16;
        f16x8 mfrag[2];
        #pragma unroll
        for (int ft = 0; ft < 2; ++ft) {
            int n = 64 * w + 32 * ft + i32;
            mfrag[ft] = *(const f16x8*)(W1t + n * 64 + kb + 8 * hi);
        }
        #pragma unroll
        for (int rt = 0; rt < 4; ++rt) {
            f16x8 hfrag = *(const f16x8*)&hA[(32 * rt + i32) * LDA + kb + 8 * hi];
            #pragma unroll
            for (int ft = 0; ft < 2; ++ft)
                acc[ft][rt] = __builtin_amdgcn_mfma_f32_32x32x16_f16(
                    mfrag[ft], hfrag, acc[ft][rt], 0, 0, 0);
        }
    }
    __syncthreads();   // all reads of mu-region done before overwrite
    #pragma unroll
    for (int ft = 0; ft < 2; ++ft) {
        const int fb = 64 * w + 32 * ft + 4 * hi;
        #pragma unroll
        for (int rt = 0; rt < 4; ++rt) {
            const int row = 32 * rt + i32;
            #pragma unroll
            for (int g = 0; g < 4; ++g) {
                const float4 bias = *(const float4*)&b1s[fb + 8 * g];
                f16x4 hv;
                hv[0] = (_Float16)fmaxf(acc[ft][rt][4 * g + 0] + bias.x, 0.f);
                hv[1] = (_Float16)fmaxf(acc[ft][rt][4 * g + 1] + bias.y, 0.f);
                hv[2] = (_Float16)fmaxf(acc[ft][rt][4 * g + 2] + bias.z, 0.f);
                hv[3] = (_Float16)fmaxf(acc[ft][rt][4 * g + 3] + bias.w, 0.f);
                *(f16x4*)&hA[row * LDA + fb + 8 * g] = hv;
            }
        }
    }

    // ================= 4 Fourier layers: h = relu(h @ M_l + x @ X_l) ==========
    #pragma unroll 1
    for (int l = 0; l < 4; ++l) {
        __syncthreads();   // hA writes from previous stage visible
        #pragma unroll
        for (int ft = 0; ft < 2; ++ft)
            #pragma unroll
            for (int rt = 0; rt < 4; ++rt)
                acc[ft][rt] = (f32x16)(0.f);

        const _Float16* Ml = Mt + (size_t)l * 256 * KAUG;
        #pragma unroll
        for (int ks = 0; ks < 18; ++ks) {
            const int kb = ks * 16;
            f16x8 mfrag[2];
            #pragma unroll
            for (int ft = 0; ft < 2; ++ft) {
                int n = 64 * w + 32 * ft + i32;
                mfrag[ft] = *(const f16x8*)(Ml + n * KAUG + kb + 8 * hi);
            }
            #pragma unroll
            for (int rt = 0; rt < 4; ++rt) {
                f16x8 hfrag = *(const f16x8*)&hA[(32 * rt + i32) * LDA + kb + 8 * hi];
                #pragma unroll
                for (int ft = 0; ft < 2; ++ft)
                    acc[ft][rt] = __builtin_amdgcn_mfma_f32_32x32x16_f16(
                        mfrag[ft], hfrag, acc[ft][rt], 0, 0, 0);
            }
        }
        __syncthreads();   // all hA reads done before overwrite
        #pragma unroll
        for (int ft = 0; ft < 2; ++ft) {
            const int fb = 64 * w + 32 * ft + 4 * hi;
            #pragma unroll
            for (int rt = 0; rt < 4; ++rt) {
                const int row = 32 * rt + i32;
                #pragma unroll
                for (int g = 0; g < 4; ++g) {
                    f16x4 hv;
                    hv[0] = (_Float16)fmaxf(acc[ft][rt][4 * g + 0], 0.f);
                    hv[1] = (_Float16)fmaxf(acc[ft][rt][4 * g + 1], 0.f);
                    hv[2] = (_Float16)fmaxf(acc[ft][rt][4 * g + 2], 0.f);
                    hv[3] = (_Float16)fmaxf(acc[ft][rt][4 * g + 3], 0.f);
                    *(f16x4*)&hA[row * LDA + fb + 8 * g] = hv;
                }
            }
        }
    }

    // ================= decoder: out = h @ W2 + b2 =============================
    __syncthreads();
    {
        const int r  = t & 127;
        const int hf = t >> 7;        // two threads per row, half the columns each
        const int n0 = hf * 128;
        float s = 0.f;
        #pragma unroll
        for (int j = 0; j < 16; ++j) {
            f16x8 v = *(const f16x8*)&hA[r * LDA + n0 + 8 * j];
            const float* wp = &W2s[n0 + 8 * j];
            s += (float)v[0] * wp[0] + (float)v[1] * wp[1]
               + (float)v[2] * wp[2] + (float)v[3] * wp[3]
               + (float)v[4] * wp[4] + (float)v[5] * wp[5]
               + (float)v[6] * wp[6] + (float)v[7] * wp[7];
        }
        if (hf) red[r] = s;
        __syncthreads();
        if (!hf) out[r0 + r] = s + red[r] + b2[0];
    }
}

// ---------------------------------------------------------------------------
extern "C" void kernel_launch(void* const* d_in, const int* in_sizes, int n_in,
                              void* d_out, int out_size, void* d_ws, size_t ws_size,
                              hipStream_t stream) {
    const float* mu = (const float*)d_in[0];
    const float* x  = (const float*)d_in[1];
    const float* W1 = (const float*)d_in[2];
    const float* b1 = (const float*)d_in[3];
    const float* fw = (const float*)d_in[4];
    const float* lw = (const float*)d_in[5];
    const float* W2 = (const float*)d_in[6];
    const float* b2 = (const float*)d_in[7];
    float* out = (float*)d_out;

    _Float16* Mt  = (_Float16*)d_ws;
    _Float16* W1t = Mt + 4 * 256 * KAUG;

    fno_precompute<<<68, 256, 0, stream>>>(W1, fw, lw, Mt, W1t);
    fno_main<<<N_B / BM, 256, 0, stream>>>(mu, x, b1, W2, b2, Mt, W1t, out);
}